// Round 1
// 1160.417 us; speedup vs baseline: 1.7236x; 1.7236x over previous
//
#include <hip/hip_runtime.h>

// Problem constants (from reference)
constexpr int kB = 4;
constexpr int kT = 4096;
constexpr int kN_TOK = kB * kT;     // 16384 tokens (GEMM M)
constexpr int kH = 4096;            // hidden (GEMM N and K)
constexpr int kE = 4;               // experts
constexpr int kR = 8;               // LoRA rank
constexpr float kSCALE = 1.0f;      // ALPHA / RANK

typedef __bf16 bf16x8 __attribute__((ext_vector_type(8)));
typedef float  f32x4  __attribute__((ext_vector_type(4)));

template <int N> struct IC { static constexpr int value = N; };

// ---- helpers ---------------------------------------------------------------

__device__ inline unsigned short f2bf(float f) {
  union { float f; unsigned u; } v; v.f = f;
  unsigned r = v.u + 0x7FFFu + ((v.u >> 16) & 1u);   // round-to-nearest-even
  return (unsigned short)(r >> 16);
}

__device__ inline unsigned pack2(float lo, float hi) {
  return (unsigned)f2bf(lo) | ((unsigned)f2bf(hi) << 16);
}

// async 16B global -> LDS (global_load_lds_dwordx4); LDS dest must be
// wave-uniform base + lane*16, which our chunk mapping guarantees.
__device__ inline void gload_lds16(const unsigned short* g, unsigned short* l) {
  __builtin_amdgcn_global_load_lds(
      (const __attribute__((address_space(1))) unsigned int*)g,
      (__attribute__((address_space(3))) unsigned int*)l, 16, 0, 0);
}

// ---- kernel 1: W_up fp32 -> bf16 ------------------------------------------

__global__ __launch_bounds__(256) void convert_w_kernel(
    const float* __restrict__ w, unsigned short* __restrict__ wb) {
  size_t i = ((size_t)blockIdx.x * 256 + threadIdx.x) * 8;
  float4 a = *(const float4*)(w + i);
  float4 b = *(const float4*)(w + i + 4);
  uint4 s;
  s.x = pack2(a.x, a.y); s.y = pack2(a.z, a.w);
  s.z = pack2(b.x, b.y); s.w = pack2(b.z, b.w);
  *(uint4*)(wb + i) = s;
}

// ---- kernel 2: routing + LoRA z + x fp32->bf16 -----------------------------
// one block (256 threads) per token. Gate: fp32 per-thread partial (16 terms,
// ~1e-6 rel err), fp64 cross-lane reduction -> argmax matches np reference.

__global__ __launch_bounds__(256) void route_kernel(
    const float* __restrict__ x, const float* __restrict__ gate_w,
    const float* __restrict__ ebias, const float* __restrict__ lora_A,
    unsigned short* __restrict__ xb, float* __restrict__ zbuf,
    int* __restrict__ top1) {
  const int n = blockIdx.x;
  const int t = threadIdx.x;
  const int lane = t & 63, wave = t >> 6;
  const float* xr = x + (size_t)n * kH;

  // load this thread's 16 elements (coalesced float4 x4)
  float4 xv[4];
#pragma unroll
  for (int k = 0; k < 4; ++k) xv[k] = *(const float4*)(xr + k * 1024 + t * 4);

  // write bf16 copy of x (coalesced 8B stores)
#pragma unroll
  for (int k = 0; k < 4; ++k) {
    uint2 p;
    p.x = pack2(xv[k].x, xv[k].y);
    p.y = pack2(xv[k].z, xv[k].w);
    *(uint2*)(xb + (size_t)n * kH + k * 1024 + t * 4) = p;
  }

  // gate logits
  double g[kE];
#pragma unroll
  for (int e = 0; e < kE; ++e) {
    float p = 0.f;
#pragma unroll
    for (int k = 0; k < 4; ++k) {
      float4 w = *(const float4*)(gate_w + (size_t)e * kH + k * 1024 + t * 4);
      p += xv[k].x * w.x + xv[k].y * w.y + xv[k].z * w.z + xv[k].w * w.w;
    }
    g[e] = (double)p;
  }
#pragma unroll
  for (int e = 0; e < kE; ++e)
    for (int off = 32; off; off >>= 1) g[e] += __shfl_down(g[e], off, 64);

  __shared__ double gs[4][kE];
  __shared__ int se;
  if (lane == 0) {
#pragma unroll
    for (int e = 0; e < kE; ++e) gs[wave][e] = g[e];
  }
  __syncthreads();
  if (t == 0) {
    double best = -1e300; int bi = 0;
#pragma unroll
    for (int e = 0; e < kE; ++e) {
      double v = gs[0][e] + gs[1][e] + gs[2][e] + gs[3][e] + (double)ebias[e];
      if (v > best) { best = v; bi = e; }   // strict > keeps first index (np.argmax)
    }
    se = bi;
    top1[n] = bi;
  }
  __syncthreads();
  const int e = se;

  // z[n, r] = dot(x[n], lora_A[e, r, :])
  const float* Ae = lora_A + (size_t)e * kR * kH;
  float zr[kR] = {0, 0, 0, 0, 0, 0, 0, 0};
#pragma unroll
  for (int r = 0; r < kR; ++r) {
#pragma unroll
    for (int k = 0; k < 4; ++k) {
      float4 w = *(const float4*)(Ae + (size_t)r * kH + k * 1024 + t * 4);
      zr[r] += xv[k].x * w.x + xv[k].y * w.y + xv[k].z * w.z + xv[k].w * w.w;
    }
  }
#pragma unroll
  for (int r = 0; r < kR; ++r)
    for (int off = 32; off; off >>= 1) zr[r] += __shfl_down(zr[r], off, 64);

  __shared__ float zs[4][kR];
  if (lane == 0) {
#pragma unroll
    for (int r = 0; r < kR; ++r) zs[wave][r] = zr[r];
  }
  __syncthreads();
  if (t < kR) zbuf[(size_t)n * kR + t] = zs[0][t] + zs[1][t] + zs[2][t] + zs[3][t];
}

// ---- kernel 3: bf16 NT GEMM, 256x256 tile, ring-4 LDS, counted vmcnt -------
// Old version (128^2, 2-barrier, implicit vmcnt(0) drain each K-step) exposed
// full L3/HBM load latency per step: 77cy MFMA/SIMD vs ~500cy drain -> 15%
// MfmaUtil. New structure (guide T3/T4/T5/T1):
//   - 256x256 tile, 8 waves (2M x 4N), BK=32, mfma_f32_16x16x32_bf16
//   - LDS ring of 4 K-tile buffers (4 x 32KB = 128KB): tile t in buf[t&3]
//   - stage(t+3) issued at step t; s_waitcnt vmcnt(12) (= 3 tiles in flight)
//     before barrier A -> tile t landed everywhere; NEVER vmcnt(0) in loop.
//   - WAR safe: buf[(t+3)&3] was last read at step t-1, whose readers passed
//     lgkmcnt(0) + barrier B before step t issues the stage.
//   - XOR chunk swizzle (slot ^= (row>>1)&3, 16B granules): applied to the
//     per-lane GLOBAL source + the LDS read offset; LDS dest stays linear
//     (global_load_lds requires base + lane*16).
//   - XCD ordering: id&7 = XCD (HW round-robin); each XCD owns 8 bm-panels,
//     bn-fastest -> A-panel (2MB) L2-resident across 16 consecutive blocks,
//     B (32MB) L3-resident. Cuts the 793MB FETCH (A re-read ~6x from HBM).

__global__ __launch_bounds__(512) void gemm_kernel(
    const unsigned short* __restrict__ A,   // xb  [16384, 4096] bf16
    const unsigned short* __restrict__ Bw,  // wb  [4096, 4096] bf16
    const float* __restrict__ zbuf,         // [16384, 8]
    const int* __restrict__ top1,           // [16384]
    const float* __restrict__ loraB,        // [E, 4096, 8]
    float* __restrict__ out) {              // [16384, 4096] fp32
  constexpr int BK = 32;
  constexpr int NT = kH / BK;               // 128 K-tiles
  __shared__ unsigned short lds[65536];     // 128 KiB: buf[t&3] = A 8192 | B 8192 elems

  const int tid = threadIdx.x;
  const int lane = tid & 63, wave = tid >> 6;
  const int wm = wave >> 2, wn = wave & 3;  // 2 x 4 wave grid
  const int lm = lane & 15, lq = lane >> 4;

  // block ordering: xcd = id&7, per-XCD 8 bm-panels, bn fastest (bijective)
  const int id = blockIdx.x;                // [0, 1024)
  const int q = id >> 3;                    // [0, 128)
  const int bn = q & 15;                    // [0, 16)
  const int bm = (id & 7) * 8 + (q >> 4);   // [0, 64)

  const unsigned short* Ab = A + (size_t)(bm * 256) * kH;
  const unsigned short* Bb = Bw + (size_t)(bn * 256) * kH;

  // staging: 1024 chunks of 16B per 16KB matrix tile; thread owns chunks
  // {tid, 512+tid}. chunk c -> (row=c>>2, slot=c&3); LDS holds global octet
  // g = slot ^ ((row>>1)&3) at slot (inverse-swizzled source, linear dest).
  int srow[2], soff[2];
#pragma unroll
  for (int j = 0; j < 2; ++j) {
    const int c = j * 512 + tid, row = c >> 2, slot = c & 3;
    srow[j] = row;
    soff[j] = (slot ^ ((row >> 1) & 3)) * 8;
  }

  // fragment read offsets (elements), swizzled to match staging
  int offA[8], offB[4];
#pragma unroll
  for (int m = 0; m < 8; ++m) {
    const int row = wm * 128 + m * 16 + lm;
    offA[m] = row * BK + (lq ^ ((row >> 1) & 3)) * 8;
  }
#pragma unroll
  for (int n = 0; n < 4; ++n) {
    const int row = wn * 64 + n * 16 + lm;
    offB[n] = 8192 + row * BK + (lq ^ ((row >> 1) & 3)) * 8;
  }

  f32x4 acc[8][4];
#pragma unroll
  for (int m = 0; m < 8; ++m)
#pragma unroll
    for (int n = 0; n < 4; ++n) acc[m][n] = (f32x4)0.0f;

  auto stage = [&](int t) {
    const int k0 = t * BK;
    unsigned short* bA = &lds[(t & 3) * 16384];
#pragma unroll
    for (int j = 0; j < 2; ++j) {
      const int c = j * 512 + tid;
      gload_lds16(Ab + (size_t)srow[j] * kH + k0 + soff[j], bA + c * 8);
      gload_lds16(Bb + (size_t)srow[j] * kH + k0 + soff[j], bA + 8192 + c * 8);
    }
  };

  auto kstep = [&](int t, auto VM) {
    // tile t's 4 loads are the oldest beyond VM outstanding -> landed; barrier
    // publishes all waves' staging. vmcnt BEFORE barrier (per-wave counter).
    asm volatile("s_waitcnt vmcnt(%0)" ::"i"((int)VM.value) : "memory");
    __builtin_amdgcn_sched_barrier(0);
    __builtin_amdgcn_s_barrier();
    __builtin_amdgcn_sched_barrier(0);
    asm volatile("" ::: "memory");          // no LDS read hoists above barrier
    const unsigned short* buf = &lds[(t & 3) * 16384];
    bf16x8 af[8], bf[4];
#pragma unroll
    for (int m = 0; m < 8; ++m) af[m] = *(const bf16x8*)(buf + offA[m]);
#pragma unroll
    for (int n = 0; n < 4; ++n) bf[n] = *(const bf16x8*)(buf + offB[n]);
    __builtin_amdgcn_s_setprio(1);
#pragma unroll
    for (int m = 0; m < 8; ++m)
#pragma unroll
      for (int n = 0; n < 4; ++n)
        acc[m][n] = __builtin_amdgcn_mfma_f32_16x16x32_bf16(
            af[m], bf[n], acc[m][n], 0, 0, 0);
    __builtin_amdgcn_s_setprio(0);
    // readers of buf[t&3] done -> step t+1 may stage into buf[(t+4)&3]
    asm volatile("s_waitcnt lgkmcnt(0)" ::: "memory");
    __builtin_amdgcn_sched_barrier(0);
    __builtin_amdgcn_s_barrier();
    __builtin_amdgcn_sched_barrier(0);
    asm volatile("" ::: "memory");
  };

  stage(0); stage(1); stage(2);             // 12 loads in flight
  int t = 0;
  for (; t < NT - 3; ++t) {
    stage(t + 3);
    kstep(t, IC<12>{});
  }
  kstep(t, IC<8>{}); ++t;                   // t = NT-3
  kstep(t, IC<4>{}); ++t;
  kstep(t, IC<0>{});

  // epilogue: C/D layout col=lane&15, row=lq*4+reg (m89/m91-verified) + LoRA
  const int rowBase = bm * 256 + wm * 128 + lq * 4;
  const int colBase = bn * 256 + wn * 64 + lm;
#pragma unroll
  for (int mt = 0; mt < 8; ++mt) {
#pragma unroll
    for (int r = 0; r < 4; ++r) {
      const int row = rowBase + mt * 16 + r;
      const int e = top1[row];
      const float4 z0 = *(const float4*)(zbuf + (size_t)row * kR);
      const float4 z1 = *(const float4*)(zbuf + (size_t)row * kR + 4);
      const float* Bp = loraB + (size_t)e * kH * kR;
      float* orow = out + (size_t)row * kH;
#pragma unroll
      for (int nt = 0; nt < 4; ++nt) {
        const int col = colBase + nt * 16;
        const float4 b0 = *(const float4*)(Bp + (size_t)col * kR);
        const float4 b1 = *(const float4*)(Bp + (size_t)col * kR + 4);
        float d = z0.x * b0.x + z0.y * b0.y + z0.z * b0.z + z0.w * b0.w +
                  z1.x * b1.x + z1.y * b1.y + z1.z * b1.z + z1.w * b1.w;
        orow[col] = acc[mt][nt][r] + d * kSCALE;
      }
    }
  }
}

// ---- launch ----------------------------------------------------------------

extern "C" void kernel_launch(void* const* d_in, const int* in_sizes, int n_in,
                              void* d_out, int out_size, void* d_ws, size_t ws_size,
                              hipStream_t stream) {
  const float* x   = (const float*)d_in[0];   // [4,4096,4096]
  const float* Wup = (const float*)d_in[1];   // [4096,4096]
  const float* gw  = (const float*)d_in[2];   // [4,4096]
  const float* eb  = (const float*)d_in[3];   // [4]
  const float* lA  = (const float*)d_in[4];   // [4,8,4096]
  const float* lB  = (const float*)d_in[5];   // [4,4096,8]
  float* out = (float*)d_out;

  // workspace layout (bytes): wb 33554432 | xb 134217728 | z 524288 | top1 65536
  char* ws = (char*)d_ws;
  unsigned short* wb = (unsigned short*)ws;
  unsigned short* xb = (unsigned short*)(ws + 33554432);
  float* zbuf        = (float*)(ws + 33554432 + 134217728);
  int* top1          = (int*)(ws + 33554432 + 134217728 + 524288);

  convert_w_kernel<<<dim3((kH * kH) / (256 * 8)), dim3(256), 0, stream>>>(Wup, wb);
  route_kernel<<<dim3(kN_TOK), dim3(256), 0, stream>>>(x, gw, eb, lA, xb, zbuf, top1);
  gemm_kernel<<<dim3((kN_TOK / 256) * (kH / 256)), dim3(512), 0, stream>>>(
      xb, wb, zbuf, top1, lB, out);
}

// Round 2
// 1087.798 us; speedup vs baseline: 1.8387x; 1.0668x over previous
//
#include <hip/hip_runtime.h>

// Problem constants (from reference)
constexpr int kB = 4;
constexpr int kT = 4096;
constexpr int kN_TOK = kB * kT;     // 16384 tokens (GEMM M)
constexpr int kH = 4096;            // hidden (GEMM N and K)
constexpr int kE = 4;               // experts
constexpr int kR = 8;               // LoRA rank
constexpr float kSCALE = 1.0f;      // ALPHA / RANK

typedef __bf16 bf16x8 __attribute__((ext_vector_type(8)));
typedef float  f32x4  __attribute__((ext_vector_type(4)));

template <int N> struct IC { static constexpr int value = N; };

// ---- helpers ---------------------------------------------------------------

__device__ inline unsigned short f2bf(float f) {
  union { float f; unsigned u; } v; v.f = f;
  unsigned r = v.u + 0x7FFFu + ((v.u >> 16) & 1u);   // round-to-nearest-even
  return (unsigned short)(r >> 16);
}

__device__ inline unsigned pack2(float lo, float hi) {
  return (unsigned)f2bf(lo) | ((unsigned)f2bf(hi) << 16);
}

// async 16B global -> LDS (global_load_lds_dwordx4); LDS dest must be
// wave-uniform base + lane*16, which our chunk mapping guarantees.
__device__ inline void gload_lds16(const unsigned short* g, unsigned short* l) {
  __builtin_amdgcn_global_load_lds(
      (const __attribute__((address_space(1))) unsigned int*)g,
      (__attribute__((address_space(3))) unsigned int*)l, 16, 0, 0);
}

// ---- kernel 1: W_up fp32 -> bf16 ------------------------------------------

__global__ __launch_bounds__(256) void convert_w_kernel(
    const float* __restrict__ w, unsigned short* __restrict__ wb) {
  size_t i = ((size_t)blockIdx.x * 256 + threadIdx.x) * 8;
  float4 a = *(const float4*)(w + i);
  float4 b = *(const float4*)(w + i + 4);
  uint4 s;
  s.x = pack2(a.x, a.y); s.y = pack2(a.z, a.w);
  s.z = pack2(b.x, b.y); s.w = pack2(b.z, b.w);
  *(uint4*)(wb + i) = s;
}

// ---- kernel 2: routing + x fp32->bf16 --------------------------------------
// one block (256 threads) per token. Gate: fp32 per-thread partial (16 terms,
// ~1e-6 rel err), fp64 cross-lane reduction -> argmax matches np reference.
// LoRA-z moved to zall_kernel (was ~60% of this kernel's global loads).

__global__ __launch_bounds__(256) void route_kernel(
    const float* __restrict__ x, const float* __restrict__ gate_w,
    const float* __restrict__ ebias,
    unsigned short* __restrict__ xb, int* __restrict__ top1) {
  const int n = blockIdx.x;
  const int t = threadIdx.x;
  const int lane = t & 63, wave = t >> 6;
  const float* xr = x + (size_t)n * kH;

  // load this thread's 16 elements (coalesced float4 x4)
  float4 xv[4];
#pragma unroll
  for (int k = 0; k < 4; ++k) xv[k] = *(const float4*)(xr + k * 1024 + t * 4);

  // write bf16 copy of x (coalesced 8B stores)
#pragma unroll
  for (int k = 0; k < 4; ++k) {
    uint2 p;
    p.x = pack2(xv[k].x, xv[k].y);
    p.y = pack2(xv[k].z, xv[k].w);
    *(uint2*)(xb + (size_t)n * kH + k * 1024 + t * 4) = p;
  }

  // gate logits
  double g[kE];
#pragma unroll
  for (int e = 0; e < kE; ++e) {
    float p = 0.f;
#pragma unroll
    for (int k = 0; k < 4; ++k) {
      float4 w = *(const float4*)(gate_w + (size_t)e * kH + k * 1024 + t * 4);
      p += xv[k].x * w.x + xv[k].y * w.y + xv[k].z * w.z + xv[k].w * w.w;
    }
    g[e] = (double)p;
  }
#pragma unroll
  for (int e = 0; e < kE; ++e)
    for (int off = 32; off; off >>= 1) g[e] += __shfl_down(g[e], off, 64);

  __shared__ double gs[4][kE];
  if (lane == 0) {
#pragma unroll
    for (int e = 0; e < kE; ++e) gs[wave][e] = g[e];
  }
  __syncthreads();
  if (t == 0) {
    double best = -1e300; int bi = 0;
#pragma unroll
    for (int e = 0; e < kE; ++e) {
      double v = gs[0][e] + gs[1][e] + gs[2][e] + gs[3][e] + (double)ebias[e];
      if (v > best) { best = v; bi = e; }   // strict > keeps first index (np.argmax)
    }
    top1[n] = bi;
  }
}

// ---- kernel 2b: z = xb @ lora_A^T (all 32 rows), select by top1 ------------
// M=16384, N=32, K=4096 skinny MFMA GEMM. Block = 64 tokens, 4 waves; wave w
// owns rows w*16..+16, all 32 cols (2 n-frags). A fp32 converted to bf16 into
// LDS per K-step. XOR octet swizzle on both tiles (conflict-free frag reads).

__global__ __launch_bounds__(256) void zall_kernel(
    const unsigned short* __restrict__ xb,  // [16384,4096] bf16
    const float* __restrict__ lora_A,       // [4,8,4096] == [32][4096] row-major
    const int* __restrict__ top1,
    float* __restrict__ zbuf) {             // [16384,8] selected z
  constexpr int BK = 64;
  constexpr int NTK = kH / BK;              // 64
  __shared__ unsigned short lsX[64 * BK];   // 8 KB
  __shared__ unsigned short lsA[32 * BK];   // 4 KB

  const int tid = threadIdx.x;
  const int lane = tid & 63, wv = tid >> 6;
  const int lm = lane & 15, lq = lane >> 4;
  const int rowBase = blockIdx.x * 64;
  const unsigned short* Xb = xb + (size_t)rowBase * kH;

  // xb staging: 512 chunks of 16B; chunk c: row=c>>3, slot=c&7; source octet
  // slot^(row&7) (inverse-swizzled source, linear LDS dest).
  const int c0 = tid, c1 = 256 + tid;
  const int r0 = c0 >> 3, s0 = ((c0 & 7) ^ (r0 & 7)) * 8;
  const int r1 = c1 >> 3, s1 = ((c1 & 7) ^ (r1 & 7)) * 8;
  // A staging: thread -> j = tid>>3 (0..31), octet o = tid&7
  const int ja = tid >> 3, oa = tid & 7;

  f32x4 a0 = {0.f, 0.f, 0.f, 0.f}, a1 = {0.f, 0.f, 0.f, 0.f};

  for (int t = 0; t < NTK; ++t) {
    const int k0 = t * BK;
    __syncthreads();                        // prev iteration's frag reads done
    gload_lds16(Xb + (size_t)r0 * kH + k0 + s0, &lsX[c0 * 8]);
    gload_lds16(Xb + (size_t)r1 * kH + k0 + s1, &lsX[c1 * 8]);
    {
      const float* src = lora_A + (size_t)ja * kH + k0 + oa * 8;
      float4 va = *(const float4*)src;
      float4 vb = *(const float4*)(src + 4);
      uint4 s;
      s.x = pack2(va.x, va.y); s.y = pack2(va.z, va.w);
      s.z = pack2(vb.x, vb.y); s.w = pack2(vb.z, vb.w);
      *(uint4*)&lsA[ja * BK + ((oa ^ (ja & 7)) * 8)] = s;
    }
    __syncthreads();                        // drains vmcnt+lgkm (compiler)

    bf16x8 ax[2], bx0[2], bx1[2];
    const int row = wv * 16 + lm;
#pragma unroll
    for (int kf = 0; kf < 2; ++kf) {
      ax[kf]  = *(const bf16x8*)&lsX[row * BK + (((kf * 4 + lq) ^ (row & 7)) * 8)];
      bx0[kf] = *(const bf16x8*)&lsA[lm * BK + (((kf * 4 + lq) ^ (lm & 7)) * 8)];
      const int j1 = 16 + lm;
      bx1[kf] = *(const bf16x8*)&lsA[j1 * BK + (((kf * 4 + lq) ^ (j1 & 7)) * 8)];
    }
#pragma unroll
    for (int kf = 0; kf < 2; ++kf) {
      a0 = __builtin_amdgcn_mfma_f32_16x16x32_bf16(ax[kf], bx0[kf], a0, 0, 0, 0);
      a1 = __builtin_amdgcn_mfma_f32_16x16x32_bf16(ax[kf], bx1[kf], a1, 0, 0, 0);
    }
  }

  // C/D layout: col=lane&15, row=lq*4+r (m89/m91-verified)
#pragma unroll
  for (int r = 0; r < 4; ++r) {
    const int row = rowBase + wv * 16 + lq * 4 + r;
    const int e = top1[row];
    if ((lm >> 3) == e)        zbuf[(size_t)row * kR + (lm & 7)] = a0[r];
    if (((16 + lm) >> 3) == e) zbuf[(size_t)row * kR + (lm & 7)] = a1[r];
  }
}

// ---- kernel 3: bf16 NT GEMM, 256x256 tile, ring-4 LDS, pipelined quadrants -
// R1 post-mortem: 2-barrier-per-tile with all-reads-then-all-MFMA hit the
// known ~36% structure ceiling (LDS 288cy + MFMA 307cy serialize per SIMD +
// 2 barriers). New schedule, 1 barrier/tile, all ds_reads in MFMA shadow:
//   kstep(t): readQ1(t) | MFMA Q0(t) | stage(t+3) | MFMA Q1(t) |
//             vmcnt(8) barrier | readQ0(t+1)
// Q0 = B-frags(4)+A m0-3(4) read post-barrier of prev step (hidden under
// barrier wait + next step's Q0 MFMA via compiler's counted lgkmcnt);
// Q1 = A m4-7 (4 reads) hidden under MFMA Q0. vmcnt(8) keeps 2-step prefetch
// distance; never drains in main loop. WAR: all reads of buf[(t-1)&3] retire
// before barrier(t-1) (compiler lgkm waits precede MFMA uses) < stage(t+3).

__global__ __launch_bounds__(512) void gemm_kernel(
    const unsigned short* __restrict__ A,   // xb  [16384, 4096] bf16
    const unsigned short* __restrict__ Bw,  // wb  [4096, 4096] bf16
    const float* __restrict__ zbuf,         // [16384, 8]
    const int* __restrict__ top1,           // [16384]
    const float* __restrict__ loraB,        // [E, 4096, 8]
    float* __restrict__ out) {              // [16384, 4096] fp32
  constexpr int BK = 32;
  constexpr int NT = kH / BK;               // 128 K-tiles
  __shared__ unsigned short lds[65536];     // 128 KiB: buf[t&3] = A 8192 | B 8192 elems

  const int tid = threadIdx.x;
  const int lane = tid & 63, wave = tid >> 6;
  const int wm = wave >> 2, wn = wave & 3;  // 2 x 4 wave grid
  const int lm = lane & 15, lq = lane >> 4;

  // block ordering: xcd = id&7, per-XCD 8 bm-panels, bn fastest (bijective)
  const int id = blockIdx.x;                // [0, 1024)
  const int q = id >> 3;                    // [0, 128)
  const int bn = q & 15;                    // [0, 16)
  const int bm = (id & 7) * 8 + (q >> 4);   // [0, 64)

  const unsigned short* Ab = A + (size_t)(bm * 256) * kH;
  const unsigned short* Bb = Bw + (size_t)(bn * 256) * kH;

  // staging: 1024 chunks of 16B per 16KB matrix tile; thread owns chunks
  // {tid, 512+tid}. chunk c -> (row=c>>2, slot=c&3); LDS holds global octet
  // g = slot ^ ((row>>1)&3) at slot (inverse-swizzled source, linear dest).
  int srow[2], soff[2];
#pragma unroll
  for (int j = 0; j < 2; ++j) {
    const int c = j * 512 + tid, row = c >> 2, slot = c & 3;
    srow[j] = row;
    soff[j] = (slot ^ ((row >> 1) & 3)) * 8;
  }

  // fragment read offsets (elements), swizzled to match staging
  int offA[8], offB[4];
#pragma unroll
  for (int m = 0; m < 8; ++m) {
    const int row = wm * 128 + m * 16 + lm;
    offA[m] = row * BK + (lq ^ ((row >> 1) & 3)) * 8;
  }
#pragma unroll
  for (int n = 0; n < 4; ++n) {
    const int row = wn * 64 + n * 16 + lm;
    offB[n] = 8192 + row * BK + (lq ^ ((row >> 1) & 3)) * 8;
  }

  f32x4 acc[8][4];
#pragma unroll
  for (int m = 0; m < 8; ++m)
#pragma unroll
    for (int n = 0; n < 4; ++n) acc[m][n] = (f32x4)0.0f;

  bf16x8 af0[4], af1[4], bf[4];

  auto stage = [&](int t) {
    const int k0 = t * BK;
    unsigned short* bA = &lds[(t & 3) * 16384];
#pragma unroll
    for (int j = 0; j < 2; ++j) {
      const int c = j * 512 + tid;
      gload_lds16(Ab + (size_t)srow[j] * kH + k0 + soff[j], bA + c * 8);
      gload_lds16(Bb + (size_t)srow[j] * kH + k0 + soff[j], bA + 8192 + c * 8);
    }
  };

  auto readQ0 = [&](const unsigned short* buf) {
#pragma unroll
    for (int n = 0; n < 4; ++n) bf[n] = *(const bf16x8*)(buf + offB[n]);
#pragma unroll
    for (int m = 0; m < 4; ++m) af0[m] = *(const bf16x8*)(buf + offA[m]);
  };
  auto readQ1 = [&](const unsigned short* buf) {
#pragma unroll
    for (int m = 0; m < 4; ++m) af1[m] = *(const bf16x8*)(buf + offA[4 + m]);
  };

  auto kstep = [&](int t, auto VM, auto STAGE, auto NEXT) {
    const unsigned short* buf = &lds[(t & 3) * 16384];
    readQ1(buf);                            // 4 reads, hidden under MFMA Q0
    __builtin_amdgcn_sched_barrier(0);
    __builtin_amdgcn_s_setprio(1);
#pragma unroll
    for (int m = 0; m < 4; ++m)
#pragma unroll
      for (int n = 0; n < 4; ++n)
        acc[m][n] = __builtin_amdgcn_mfma_f32_16x16x32_bf16(
            af0[m], bf[n], acc[m][n], 0, 0, 0);
    __builtin_amdgcn_s_setprio(0);
    __builtin_amdgcn_sched_barrier(0);
    if constexpr (STAGE.value) stage(t + 3);  // VMEM issue under MFMA shadow
    __builtin_amdgcn_sched_barrier(0);
    __builtin_amdgcn_s_setprio(1);
#pragma unroll
    for (int m = 0; m < 4; ++m)
#pragma unroll
      for (int n = 0; n < 4; ++n)
        acc[4 + m][n] = __builtin_amdgcn_mfma_f32_16x16x32_bf16(
            af1[m], bf[n], acc[4 + m][n], 0, 0, 0);
    __builtin_amdgcn_s_setprio(0);
    __builtin_amdgcn_sched_barrier(0);
    if constexpr (NEXT.value) {
      // publish tile t+1 (its 4 loads are oldest beyond VM outstanding)
      asm volatile("s_waitcnt vmcnt(%0)" ::"i"((int)VM.value) : "memory");
      __builtin_amdgcn_sched_barrier(0);
      __builtin_amdgcn_s_barrier();
      __builtin_amdgcn_sched_barrier(0);
      asm volatile("" ::: "memory");
      readQ0(&lds[((t + 1) & 3) * 16384]);  // 8 reads, hidden under next Q0 MFMA
      __builtin_amdgcn_sched_barrier(0);
    }
  };

  stage(0); stage(1); stage(2);             // 12 loads in flight
  asm volatile("s_waitcnt vmcnt(8)" ::: "memory");   // tile 0 landed
  __builtin_amdgcn_sched_barrier(0);
  __builtin_amdgcn_s_barrier();
  __builtin_amdgcn_sched_barrier(0);
  asm volatile("" ::: "memory");
  readQ0(&lds[0]);
  __builtin_amdgcn_sched_barrier(0);

  int t = 0;
  for (; t < NT - 3; ++t) kstep(t, IC<8>{}, IC<1>{}, IC<1>{});
  kstep(t, IC<4>{}, IC<0>{}, IC<1>{}); ++t;   // t = NT-3: {NT-2,NT-1} in flight
  kstep(t, IC<0>{}, IC<0>{}, IC<1>{}); ++t;   // t = NT-2: wait last tile
  kstep(t, IC<0>{}, IC<0>{}, IC<0>{});        // t = NT-1: no barrier/readQ0

  // epilogue: C/D layout col=lane&15, row=lq*4+reg (m89/m91-verified) + LoRA
  const int rowBase = bm * 256 + wm * 128 + lq * 4;
  const int colBase = bn * 256 + wn * 64 + lm;
#pragma unroll
  for (int mt = 0; mt < 8; ++mt) {
#pragma unroll
    for (int r = 0; r < 4; ++r) {
      const int row = rowBase + mt * 16 + r;
      const int e = top1[row];
      const float4 z0 = *(const float4*)(zbuf + (size_t)row * kR);
      const float4 z1 = *(const float4*)(zbuf + (size_t)row * kR + 4);
      const float* Bp = loraB + (size_t)e * kH * kR;
      float* orow = out + (size_t)row * kH;
#pragma unroll
      for (int nt = 0; nt < 4; ++nt) {
        const int col = colBase + nt * 16;
        const float4 b0 = *(const float4*)(Bp + (size_t)col * kR);
        const float4 b1 = *(const float4*)(Bp + (size_t)col * kR + 4);
        float d = z0.x * b0.x + z0.y * b0.y + z0.z * b0.z + z0.w * b0.w +
                  z1.x * b1.x + z1.y * b1.y + z1.z * b1.z + z1.w * b1.w;
        orow[col] = acc[mt][nt][r] + d * kSCALE;
      }
    }
  }
}

// ---- launch ----------------------------------------------------------------

extern "C" void kernel_launch(void* const* d_in, const int* in_sizes, int n_in,
                              void* d_out, int out_size, void* d_ws, size_t ws_size,
                              hipStream_t stream) {
  const float* x   = (const float*)d_in[0];   // [4,4096,4096]
  const float* Wup = (const float*)d_in[1];   // [4096,4096]
  const float* gw  = (const float*)d_in[2];   // [4,4096]
  const float* eb  = (const float*)d_in[3];   // [4]
  const float* lA  = (const float*)d_in[4];   // [4,8,4096]
  const float* lB  = (const float*)d_in[5];   // [4,4096,8]
  float* out = (float*)d_out;

  // workspace layout (bytes): wb 33554432 | xb 134217728 | z 524288 | top1 65536
  char* ws = (char*)d_ws;
  unsigned short* wb = (unsigned short*)ws;
  unsigned short* xb = (unsigned short*)(ws + 33554432);
  float* zbuf        = (float*)(ws + 33554432 + 134217728);
  int* top1          = (int*)(ws + 33554432 + 134217728 + 524288);

  convert_w_kernel<<<dim3((kH * kH) / (256 * 8)), dim3(256), 0, stream>>>(Wup, wb);
  route_kernel<<<dim3(kN_TOK), dim3(256), 0, stream>>>(x, gw, eb, xb, top1);
  zall_kernel<<<dim3(kN_TOK / 64), dim3(256), 0, stream>>>(xb, lA, top1, zbuf);
  gemm_kernel<<<dim3((kN_TOK / 256) * (kH / 256)), dim3(512), 0, stream>>>(
      xb, wb, zbuf, top1, lB, out);
}